// Round 9
// baseline (5044.270 us; speedup 1.0000x reference)
//
#include <hip/hip_runtime.h>
#include <stdint.h>

#define TN 512
#define HN 512
#define BN 64

typedef _Float16 half8 __attribute__((ext_vector_type(8)));
typedef float floatx4 __attribute__((ext_vector_type(4)));

// ---- ws layout (bytes) ----
// xb  [512 t][4 kt][4 bt][64 lane][8 j] fp16   =  8,388,608
// h0b [512 t][16 kt][4 bt][64][8] fp16         = 33,554,432
// h1b same                                     = 33,554,432
// a0p [32 b][4 rt][20 kt][64][8] fp16          =  2,621,440
// a1p [32 b][4 rt][32 kt][64][8] fp16          =  4,194,304
// f0  [64 row][512 s] u32  (row = b*2 + p)     =    131,072   (per-producer lines)
// f1  same                                     =    131,072
#define XB_OFF  (0ULL)
#define H0_OFF  (8388608ULL)
#define H1_OFF  (41943040ULL)
#define A0_OFF  (75497472ULL)
#define A1_OFF  (78118912ULL)
#define F0_OFF  (82313216ULL)
#define F1_OFF  (82444288ULL)

__device__ __forceinline__ float sigm(float x) { return 1.f / (1.f + __expf(-x)); }
__device__ __forceinline__ float tanh_(float x) {
    float e = __expf(2.f * x);
    return 1.f - 2.f / (e + 1.f);
}

// x[b][t][d] fp32 -> B-frag tiles xb[t][kt][bt][lane][j]  (verified R4-R8)
__global__ __launch_bounds__(256) void pack_x(const float* __restrict__ x, uint32_t* __restrict__ xb) {
    const int bx = blockIdx.x;                 // t*16 + kt*4 + bt
    const int t = bx >> 4, kt = (bx >> 2) & 3, bt = bx & 3;
    const int tid = threadIdx.x;
    const int jp = tid & 3, lane = tid >> 2;
    const int n = bt * 16 + (lane & 15);
    const int k = kt * 32 + (lane >> 4) * 8 + jp * 2;
    const float* src = x + ((size_t)n * TN + t) * 128 + k;
    union { _Float16 h[2]; uint32_t u; } z;
    z.h[0] = (_Float16)src[0]; z.h[1] = (_Float16)src[1];
    xb[((size_t)bx * 64 + lane) * 4 + jp] = z.u;
}

// W -> A-frags for 16-unit blocks (verified R8). Local row r = ui*4 + g so a 16x16
// C tile (rt) gives lane(quad,nl): unit = rt*4+quad, gates = the 4 C regs.
__global__ __launch_bounds__(256) void pack_a(const float* __restrict__ Wih, const float* __restrict__ Whh,
                                              int kin, int nkt, uint32_t* __restrict__ ap) {
    const int bx = blockIdx.x;                 // b*(4*nkt) + rt*nkt + kt
    const int kt = bx % nkt;
    const int rt = (bx / nkt) & 3;
    const int b  = bx / (nkt * 4);
    const int tid = threadIdx.x;
    const int jp = tid & 3, lane = tid >> 2;
    const int nl = lane & 15, quad = lane >> 4;
    const int r = rt * 16 + nl;
    const int k = kt * 32 + quad * 8 + jp * 2;
    const int grow = (r & 3) * 512 + b * 16 + (r >> 2);
    float v0, v1;
    if (k < kin) { v0 = Wih[(size_t)grow * kin + k];       v1 = Wih[(size_t)grow * kin + k + 1]; }
    else         { v0 = Whh[(size_t)grow * 512 + k - kin]; v1 = Whh[(size_t)grow * 512 + k - kin + 1]; }
    union { _Float16 h[2]; uint32_t u; } z;
    z.h[0] = (_Float16)v0; z.h[1] = (_Float16)v1;
    ap[(size_t)bx * 256 + lane * 4 + jp] = z.u;
}

// One LSTM layer on 32 blocks; block owns units u0=16b..16b+15.
// Wave w=(p=w&1,q=w>>1): bt in {2p,2p+1}, ktiles [q*NQ, q*NQ+NQ).
// Chain-minimized sync: 2 barriers/step; flag released per-(block,p) by the wave
// that stored the h data (own vmcnt drain only); dedicated poller wave w7 polls
// for step s+1 concurrently with q0's cell+publish of step s.
template<int NQ, int NSRC0>
__device__ __forceinline__ void run_layer(
    int b, int p, int q, int l, int quad, int nl,
    const uint4* __restrict__ src0, const uint4* __restrict__ src1,
    const uint4* __restrict__ apL, uint4* hout,
    const float* __restrict__ bi, const float* __restrict__ bh,
    uint32_t* fout, const uint32_t* f_in0, int t0, const uint32_t* f_in1,
    float4 (*parts)[8][64])
{
    constexpr int NKT = 4 * NQ;
    const int u0 = b * 16;

    half8 A[4][NQ];
#pragma unroll
    for (int rt = 0; rt < 4; ++rt)
#pragma unroll
        for (int kk = 0; kk < NQ; ++kk)
            A[rt][kk] = __builtin_bit_cast(half8,
                apL[(((size_t)b * 4 + rt) * NKT + q * NQ + kk) * 64 + l]);

    float bias[4][4];
    float cst[2][4];
    if (q == 0) {
#pragma unroll
        for (int rt = 0; rt < 4; ++rt)
#pragma unroll
            for (int g = 0; g < 4; ++g) {
                int grow = g * 512 + u0 + rt * 4 + quad;
                bias[rt][g] = bi[grow] + bh[grow];
            }
#pragma unroll
        for (int i2 = 0; i2 < 2; ++i2)
#pragma unroll
            for (int rt = 0; rt < 4; ++rt) cst[i2][rt] = 0.f;
    }

    for (int s = 0; s < TN; ++s) {
        // ---- dedicated poller (w7 = p1,q3): 64 lanes watch 64 producer rows ----
        if (p == 1 && q == 3) {
            const int col0 = s + t0;
            const bool needA = (col0 >= 0);
            const bool needB = (f_in1 != nullptr) && (s > 0);
            if (needA || needB) {
                for (int it = 0; it < 1024; ++it) {   // bounded: ~0.3 ms worst case
                    uint32_t a = needA ? __hip_atomic_load(f_in0 + (size_t)l * TN + col0,
                                         __ATOMIC_RELAXED, __HIP_MEMORY_SCOPE_AGENT) : 1u;
                    uint32_t c = needB ? __hip_atomic_load(f_in1 + (size_t)l * TN + (s - 1),
                                         __ATOMIC_RELAXED, __HIP_MEMORY_SCOPE_AGENT) : 1u;
                    if (__all((a & c) != 0u)) break;
                    __builtin_amdgcn_s_sleep(1);
                }
                __atomic_signal_fence(__ATOMIC_SEQ_CST);
            }
        }
        __syncthreads();                              // B1: inputs ready; parts(s-1) consumed

        // ---- MFMA: B loaded once per (bt,kt), reused over 4 rt ----
        floatx4 acc[2][4];
#pragma unroll
        for (int bi2 = 0; bi2 < 2; ++bi2)
#pragma unroll
            for (int rt = 0; rt < 4; ++rt) acc[bi2][rt] = floatx4{0.f, 0.f, 0.f, 0.f};

#pragma unroll
        for (int kk = 0; kk < NQ; ++kk) {
            const int kt = q * NQ + kk;
#pragma unroll
            for (int bi2 = 0; bi2 < 2; ++bi2) {
                const int bt = 2 * p + bi2;
                uint4 bv; bool have = true;
                if (kt < NSRC0)      bv = src0[(((size_t)s * NSRC0 + kt) * 4 + bt) * 64 + l];
                else if (s > 0)      bv = src1[(((size_t)(s - 1) * 16 + (kt - NSRC0)) * 4 + bt) * 64 + l];
                else                 have = false;
                if (have) {
                    half8 B = __builtin_bit_cast(half8, bv);
#pragma unroll
                    for (int rt = 0; rt < 4; ++rt)
                        acc[bi2][rt] = __builtin_amdgcn_mfma_f32_16x16x32_f16(A[rt][kk], B, acc[bi2][rt], 0, 0, 0);
                }
            }
        }

        if (q > 0) {
            const int wslot = (q - 1) * 2 + p;        // 0..5
#pragma unroll
            for (int bi2 = 0; bi2 < 2; ++bi2)
#pragma unroll
                for (int rt = 0; rt < 4; ++rt) {
                    float4 v;
                    v.x = acc[bi2][rt][0]; v.y = acc[bi2][rt][1];
                    v.z = acc[bi2][rt][2]; v.w = acc[bi2][rt][3];
                    parts[wslot][bi2 * 4 + rt][l] = v;
                }
        }
        __syncthreads();                              // B2: parts visible

        // ---- reduce + cell + publish + own-flag release (q==0 waves) ----
        if (q == 0) {
#pragma unroll
            for (int bi2 = 0; bi2 < 2; ++bi2) {
                const int bt = 2 * p + bi2;
#pragma unroll
                for (int rt = 0; rt < 4; ++rt) {
                    const int ti = bi2 * 4 + rt;
                    float4 v0 = parts[p][ti][l], v1 = parts[2 + p][ti][l], v2 = parts[4 + p][ti][l];
                    float gi = acc[bi2][rt][0] + v0.x + v1.x + v2.x + bias[rt][0];
                    float gf = acc[bi2][rt][1] + v0.y + v1.y + v2.y + bias[rt][1];
                    float gg = acc[bi2][rt][2] + v0.z + v1.z + v2.z + bias[rt][2];
                    float go = acc[bi2][rt][3] + v0.w + v1.w + v2.w + bias[rt][3];
                    float c = sigm(gf) * cst[bi2][rt] + sigm(gi) * tanh_(gg);
                    cst[bi2][rt] = c;
                    float h = sigm(go) * tanh_(c);
                    union { _Float16 hf; uint16_t u; } cv; cv.hf = (_Float16)h;
                    uint32_t myu = cv.u;
                    uint32_t a32 = myu | (((uint32_t)__shfl_xor((int)myu, 16)) << 16);
                    uint32_t h32 = (uint32_t)__shfl_xor((int)a32, 32);
                    if (quad == 0) {                  // 4 units -> one aligned 8B store
                        const int kt_g = (u0 + rt * 4) >> 5;
                        const int base = (u0 & 31) + rt * 4;   // 0,4,..,28
                        uint64_t val = (uint64_t)a32 | ((uint64_t)h32 << 32);
                        uint64_t* dst = (uint64_t*)((char*)hout +
                            ((((size_t)s * 16 + kt_g) * 4 + bt) * 64 + ((base >> 3) * 16 + nl)) * 16
                            + (base & 7) * 2);
                        __hip_atomic_store(dst, val, __ATOMIC_RELAXED, __HIP_MEMORY_SCOPE_AGENT);
                    }
                }
            }
            // release orders THIS wave's h stores (vmcnt drain is wave-local);
            // poller requires both p-rows of every block, so coverage is complete.
            if (l == 0)
                __hip_atomic_store(fout + (size_t)(b * 2 + p) * TN + s, 1u,
                                   __ATOMIC_RELEASE, __HIP_MEMORY_SCOPE_AGENT);
        }
    }
}

// 64 blocks x 512 threads, 1 block/CU. Blocks 0-31: layer 0; 32-63: layer 1.
__global__ __launch_bounds__(512, 2) void lstm2(
    const uint4* __restrict__ xb, uint4* h0b, uint4* h1b,
    const uint4* __restrict__ a0p, const uint4* __restrict__ a1p,
    const float* __restrict__ bih0, const float* __restrict__ bhh0,
    const float* __restrict__ bih1, const float* __restrict__ bhh1,
    uint32_t* f0, uint32_t* f1)
{
    __shared__ float4 parts[6][8][64];                // 48 KB
    const int tid = threadIdx.x;
    const int l = tid & 63;
    const int w = __builtin_amdgcn_readfirstlane(tid >> 6);
    const int p = w & 1, q = w >> 1;
    const int quad = l >> 4, nl = l & 15;
    const int blk = blockIdx.x;
    if (blk < 32)
        run_layer<5, 4>(blk, p, q, l, quad, nl, xb, h0b, a0p, h0b, bih0, bhh0,
                        f0, f0, -1, nullptr, parts);
    else
        run_layer<8, 16>(blk - 32, p, q, l, quad, nl, h0b, h1b, a1p, h1b, bih1, bhh1,
                         f1, f0, 0, f1, parts);
}

// out[n][o] = sum_k h1[T-1][k][n] * Wfc[o][k] + bfc[o]  (B-frag tile layout)
__global__ __launch_bounds__(256) void fc_kernel(const uint16_t* __restrict__ h1b,
                                                 const float* __restrict__ Wfc,
                                                 const float* __restrict__ bfc,
                                                 float* __restrict__ out) {
    const int o = blockIdx.x, tid = threadIdx.x;
    const int bb = tid & 63, kq = tid >> 6;
    float p = 0.f;
    for (int k = kq * 128; k < kq * 128 + 128; ++k) {
        size_t idx = ((((size_t)511 * 16 + (k >> 5)) * 4 + (bb >> 4)) * 64
                      + ((k >> 3) & 3) * 16 + (bb & 15)) * 8 + (k & 7);
        _Float16 hv = ((const _Float16*)h1b)[idx];
        p = fmaf((float)hv, Wfc[(size_t)o * HN + k], p);
    }
    __shared__ float red[4][64];
    red[kq][bb] = p;
    __syncthreads();
    if (tid < 64)
        out[(size_t)tid * 128 + o] = bfc[o] + red[0][tid] + red[1][tid] + red[2][tid] + red[3][tid];
}

extern "C" void kernel_launch(void* const* d_in, const int* in_sizes, int n_in,
                              void* d_out, int out_size, void* d_ws, size_t ws_size,
                              hipStream_t stream) {
    const float* x    = (const float*)d_in[0];
    const float* Wih0 = (const float*)d_in[1];
    const float* Whh0 = (const float*)d_in[2];
    const float* bih0 = (const float*)d_in[3];
    const float* bhh0 = (const float*)d_in[4];
    const float* Wih1 = (const float*)d_in[5];
    const float* Whh1 = (const float*)d_in[6];
    const float* bih1 = (const float*)d_in[7];
    const float* bhh1 = (const float*)d_in[8];
    const float* Wfc  = (const float*)d_in[9];
    const float* bfc  = (const float*)d_in[10];

    char* ws = (char*)d_ws;
    uint32_t* xb  = (uint32_t*)(ws + XB_OFF);
    uint4*    h0b = (uint4*)(ws + H0_OFF);
    uint4*    h1b = (uint4*)(ws + H1_OFF);
    uint32_t* a0p = (uint32_t*)(ws + A0_OFF);
    uint32_t* a1p = (uint32_t*)(ws + A1_OFF);
    uint32_t* f0  = (uint32_t*)(ws + F0_OFF);
    uint32_t* f1  = (uint32_t*)(ws + F1_OFF);

    hipMemsetAsync(f0, 0, 262144, stream);            // f0 + f1 (adjacent)

    hipLaunchKernelGGL(pack_x, dim3(TN * 16), dim3(256), 0, stream, x, xb);
    hipLaunchKernelGGL(pack_a, dim3(32 * 4 * 20), dim3(256), 0, stream, Wih0, Whh0, 128, 20, a0p);
    hipLaunchKernelGGL(pack_a, dim3(32 * 4 * 32), dim3(256), 0, stream, Wih1, Whh1, 512, 32, a1p);

    const uint4* xbc = (const uint4*)xb;
    const uint4* a0c = (const uint4*)a0p;
    const uint4* a1c = (const uint4*)a1p;
    void* args[] = { &xbc, &h0b, &h1b, &a0c, &a1c,
                     &bih0, &bhh0, &bih1, &bhh1, &f0, &f1 };
    hipLaunchCooperativeKernel((void*)lstm2, dim3(64), dim3(512), args, 0, stream);

    hipLaunchKernelGGL(fc_kernel, dim3(128), dim3(256), 0, stream,
                       (const uint16_t*)h1b, Wfc, bfc, (float*)d_out);
}

// Round 11
// 4441.741 us; speedup vs baseline: 1.1357x; 1.1357x over previous
//
#include <hip/hip_runtime.h>
#include <stdint.h>

#define TN 512
#define HN 512
#define BN 64

typedef _Float16 half8 __attribute__((ext_vector_type(8)));
typedef float floatx4 __attribute__((ext_vector_type(4)));

// ---- ws layout (bytes) ----
// xb  [512 t][4 kt][4 bt][64 lane][8 j] fp16   =  8,388,608
// h0b [512 t][16 kt][4 bt][64][8] fp16         = 33,554,432   (sentinel-initialized)
// h1b same                                     = 33,554,432   (sentinel-initialized)
// a0p [32 b][4 rt][20 kt][64][8] fp16          =  2,621,440
// a1p [32 b][4 rt][32 kt][64][8] fp16          =  4,194,304
#define XB_OFF  (0ULL)
#define H0_OFF  (8388608ULL)
#define H1_OFF  (41943040ULL)
#define A0_OFF  (75497472ULL)
#define A1_OFF  (78118912ULL)

#define SENT 0xFFFFFFFFFFFFFFFFULL

__device__ __forceinline__ float sigm(float x) { return 1.f / (1.f + __expf(-x)); }
__device__ __forceinline__ float tanh_(float x) {
    float e = __expf(2.f * x);
    return 1.f - 2.f / (e + 1.f);
}

// Poll one 16B tile-slice as two 8B words until neither is sentinel (wave-coherent).
// Budget is wave-uniform; on exhaustion we consume whatever is there (NaN -> wrong
// answer, terminates). Live state while spinning: 2 u64 + addresses only.
__device__ __forceinline__ uint4 poll16(const uint64_t* pw, int& budget) {
    uint64_t lo = __hip_atomic_load(pw,     __ATOMIC_RELAXED, __HIP_MEMORY_SCOPE_AGENT);
    uint64_t hi = __hip_atomic_load(pw + 1, __ATOMIC_RELAXED, __HIP_MEMORY_SCOPE_AGENT);
    while (!__all((lo != SENT) && (hi != SENT))) {
        if (--budget < 0) break;
        __builtin_amdgcn_s_sleep(1);
        lo = __hip_atomic_load(pw,     __ATOMIC_RELAXED, __HIP_MEMORY_SCOPE_AGENT);
        hi = __hip_atomic_load(pw + 1, __ATOMIC_RELAXED, __HIP_MEMORY_SCOPE_AGENT);
    }
    uint4 v;
    v.x = (uint32_t)lo; v.y = (uint32_t)(lo >> 32);
    v.z = (uint32_t)hi; v.w = (uint32_t)(hi >> 32);
    return v;
}

// x[b][t][d] fp32 -> B-frag tiles xb[t][kt][bt][lane][j]  (verified R4-R9)
__global__ __launch_bounds__(256) void pack_x(const float* __restrict__ x, uint32_t* __restrict__ xb) {
    const int bx = blockIdx.x;                 // t*16 + kt*4 + bt
    const int t = bx >> 4, kt = (bx >> 2) & 3, bt = bx & 3;
    const int tid = threadIdx.x;
    const int jp = tid & 3, lane = tid >> 2;
    const int n = bt * 16 + (lane & 15);
    const int k = kt * 32 + (lane >> 4) * 8 + jp * 2;
    const float* src = x + ((size_t)n * TN + t) * 128 + k;
    union { _Float16 h[2]; uint32_t u; } z;
    z.h[0] = (_Float16)src[0]; z.h[1] = (_Float16)src[1];
    xb[((size_t)bx * 64 + lane) * 4 + jp] = z.u;
}

// W -> A-frags for 16-unit blocks (verified R8/R9). Local row r = ui*4 + g so a
// 16x16 C tile (rt) gives lane(quad,nl): unit = rt*4+quad, gates = the 4 C regs.
__global__ __launch_bounds__(256) void pack_a(const float* __restrict__ Wih, const float* __restrict__ Whh,
                                              int kin, int nkt, uint32_t* __restrict__ ap) {
    const int bx = blockIdx.x;                 // b*(4*nkt) + rt*nkt + kt
    const int kt = bx % nkt;
    const int rt = (bx / nkt) & 3;
    const int b  = bx / (nkt * 4);
    const int tid = threadIdx.x;
    const int jp = tid & 3, lane = tid >> 2;
    const int nl = lane & 15, quad = lane >> 4;
    const int r = rt * 16 + nl;
    const int k = kt * 32 + quad * 8 + jp * 2;
    const int grow = (r & 3) * 512 + b * 16 + (r >> 2);
    float v0, v1;
    if (k < kin) { v0 = Wih[(size_t)grow * kin + k];       v1 = Wih[(size_t)grow * kin + k + 1]; }
    else         { v0 = Whh[(size_t)grow * 512 + k - kin]; v1 = Whh[(size_t)grow * 512 + k - kin + 1]; }
    union { _Float16 h[2]; uint32_t u; } z;
    z.h[0] = (_Float16)v0; z.h[1] = (_Float16)v1;
    ap[(size_t)bx * 256 + lane * 4 + jp] = z.u;
}

// One LSTM layer on 32 blocks; block owns units u0=16b..16b+15.
// Wave w=(p=w&1,q=w>>1): bt in {2p,2p+1}, ktiles [q*NQ, (q+1)*NQ).
// DATA-AS-FLAG, fused poll+consume: per tile, poll its 16B (2x8B atomic loads)
// until non-sentinel, then immediately MFMA. No flags, no release drains.
template<int NQ, int NSRC0, bool POLL0>
__device__ __forceinline__ void run_layer(
    int b, int p, int q, int l, int quad, int nl,
    const uint4* __restrict__ src0, const uint4* __restrict__ src1,
    const uint4* __restrict__ apL, uint4* hout,
    const float* __restrict__ bi, const float* __restrict__ bh,
    float4 (*parts)[8][64])
{
    constexpr int NKT = 4 * NQ;
    const int u0 = b * 16;

    float bias[4][4];
    float cst[2][4];
    if (q == 0) {
#pragma unroll
        for (int rt = 0; rt < 4; ++rt)
#pragma unroll
            for (int g = 0; g < 4; ++g) {
                int grow = g * 512 + u0 + rt * 4 + quad;
                bias[rt][g] = bi[grow] + bh[grow];
            }
#pragma unroll
        for (int i2 = 0; i2 < 2; ++i2)
#pragma unroll
            for (int rt = 0; rt < 4; ++rt) cst[i2][rt] = 0.f;
    }

    for (int s = 0; s < TN; ++s) {
        __syncthreads();                              // B1: parts WAR protection

        floatx4 acc[2][4];
#pragma unroll
        for (int bi2 = 0; bi2 < 2; ++bi2)
#pragma unroll
            for (int rt = 0; rt < 4; ++rt) acc[bi2][rt] = floatx4{0.f, 0.f, 0.f, 0.f};

        int budget = 4096;                            // wave-uniform per-step poll budget
#pragma unroll
        for (int kk = 0; kk < NQ; ++kk) {
            const int kt = q * NQ + kk;
            half8 Ak[4];
#pragma unroll
            for (int rt = 0; rt < 4; ++rt)
                Ak[rt] = __builtin_bit_cast(half8,
                    apL[(((size_t)b * 4 + rt) * NKT + kt) * 64 + l]);
#pragma unroll
            for (int bi2 = 0; bi2 < 2; ++bi2) {
                const int bt = 2 * p + bi2;
                uint4 bv;
                if (kt < NSRC0) {
                    const uint4* t = &src0[(((size_t)s * NSRC0 + kt) * 4 + bt) * 64 + l];
                    bv = POLL0 ? poll16((const uint64_t*)t, budget) : *t;
                } else if (s > 0) {
                    const uint4* t = &src1[(((size_t)(s - 1) * 16 + (kt - NSRC0)) * 4 + bt) * 64 + l];
                    bv = poll16((const uint64_t*)t, budget);
                } else {
                    bv = uint4{0u, 0u, 0u, 0u};
                }
                half8 B = __builtin_bit_cast(half8, bv);
#pragma unroll
                for (int rt = 0; rt < 4; ++rt)
                    acc[bi2][rt] = __builtin_amdgcn_mfma_f32_16x16x32_f16(Ak[rt], B, acc[bi2][rt], 0, 0, 0);
            }
        }

        if (q > 0) {
            const int wslot = (q - 1) * 2 + p;        // 0..5
#pragma unroll
            for (int bi2 = 0; bi2 < 2; ++bi2)
#pragma unroll
                for (int rt = 0; rt < 4; ++rt) {
                    float4 v;
                    v.x = acc[bi2][rt][0]; v.y = acc[bi2][rt][1];
                    v.z = acc[bi2][rt][2]; v.w = acc[bi2][rt][3];
                    parts[wslot][bi2 * 4 + rt][l] = v;
                }
        }
        __syncthreads();                              // B2: parts visible

        // ---- reduce + cell + publish (q==0). Stores ARE the signal. ----
        if (q == 0) {
#pragma unroll
            for (int bi2 = 0; bi2 < 2; ++bi2) {
                const int bt = 2 * p + bi2;
#pragma unroll
                for (int rt = 0; rt < 4; ++rt) {
                    const int ti = bi2 * 4 + rt;
                    float4 v0 = parts[p][ti][l], v1 = parts[2 + p][ti][l], v2 = parts[4 + p][ti][l];
                    float gi = acc[bi2][rt][0] + v0.x + v1.x + v2.x + bias[rt][0];
                    float gf = acc[bi2][rt][1] + v0.y + v1.y + v2.y + bias[rt][1];
                    float gg = acc[bi2][rt][2] + v0.z + v1.z + v2.z + bias[rt][2];
                    float go = acc[bi2][rt][3] + v0.w + v1.w + v2.w + bias[rt][3];
                    float c = sigm(gf) * cst[bi2][rt] + sigm(gi) * tanh_(gg);
                    cst[bi2][rt] = c;
                    float h = sigm(go) * tanh_(c);
                    union { _Float16 hf; uint16_t u; } cv; cv.hf = (_Float16)h;
                    uint32_t myu = cv.u;
                    uint32_t a32 = myu | (((uint32_t)__shfl_xor((int)myu, 16)) << 16);
                    uint32_t h32 = (uint32_t)__shfl_xor((int)a32, 32);
                    if (quad == 0) {                  // 4 units -> one aligned 8B atomic store
                        const int kt_g = (u0 + rt * 4) >> 5;
                        const int base = (u0 & 31) + rt * 4;   // 0,4,..,28
                        uint64_t val = (uint64_t)a32 | ((uint64_t)h32 << 32);
                        uint64_t* dst = (uint64_t*)((char*)hout +
                            ((((size_t)s * 16 + kt_g) * 4 + bt) * 64 + ((base >> 3) * 16 + nl)) * 16
                            + (base & 7) * 2);
                        __hip_atomic_store(dst, val, __ATOMIC_RELAXED, __HIP_MEMORY_SCOPE_AGENT);
                    }
                }
            }
        }
    }
}

// 64 blocks x 512 threads, 1 block/CU. Blocks 0-31: layer 0; 32-63: layer 1.
__global__ __launch_bounds__(512, 2) void lstm2(
    const uint4* __restrict__ xb, uint4* h0b, uint4* h1b,
    const uint4* __restrict__ a0p, const uint4* __restrict__ a1p,
    const float* __restrict__ bih0, const float* __restrict__ bhh0,
    const float* __restrict__ bih1, const float* __restrict__ bhh1)
{
    __shared__ float4 parts[6][8][64];                // 48 KB
    const int tid = threadIdx.x;
    const int l = tid & 63;
    const int w = __builtin_amdgcn_readfirstlane(tid >> 6);
    const int p = w & 1, q = w >> 1;
    const int quad = l >> 4, nl = l & 15;
    const int blk = blockIdx.x;
    if (blk < 32)
        run_layer<5, 4, false>(blk, p, q, l, quad, nl, xb, h0b, a0p, h0b, bih0, bhh0, parts);
    else
        run_layer<8, 16, true>(blk - 32, p, q, l, quad, nl, h0b, h1b, a1p, h1b, bih1, bhh1, parts);
}

// out[n][o] = sum_k h1[T-1][k][n] * Wfc[o][k] + bfc[o]  (B-frag tile layout)
__global__ __launch_bounds__(256) void fc_kernel(const uint16_t* __restrict__ h1b,
                                                 const float* __restrict__ Wfc,
                                                 const float* __restrict__ bfc,
                                                 float* __restrict__ out) {
    const int o = blockIdx.x, tid = threadIdx.x;
    const int bb = tid & 63, kq = tid >> 6;
    float p = 0.f;
    for (int k = kq * 128; k < kq * 128 + 128; ++k) {
        size_t idx = ((((size_t)511 * 16 + (k >> 5)) * 4 + (bb >> 4)) * 64
                      + ((k >> 3) & 3) * 16 + (bb & 15)) * 8 + (k & 7);
        _Float16 hv = ((const _Float16*)h1b)[idx];
        p = fmaf((float)hv, Wfc[(size_t)o * HN + k], p);
    }
    __shared__ float red[4][64];
    red[kq][bb] = p;
    __syncthreads();
    if (tid < 64)
        out[(size_t)tid * 128 + o] = bfc[o] + red[0][tid] + red[1][tid] + red[2][tid] + red[3][tid];
}

extern "C" void kernel_launch(void* const* d_in, const int* in_sizes, int n_in,
                              void* d_out, int out_size, void* d_ws, size_t ws_size,
                              hipStream_t stream) {
    const float* x    = (const float*)d_in[0];
    const float* Wih0 = (const float*)d_in[1];
    const float* Whh0 = (const float*)d_in[2];
    const float* bih0 = (const float*)d_in[3];
    const float* bhh0 = (const float*)d_in[4];
    const float* Wih1 = (const float*)d_in[5];
    const float* Whh1 = (const float*)d_in[6];
    const float* bih1 = (const float*)d_in[7];
    const float* bhh1 = (const float*)d_in[8];
    const float* Wfc  = (const float*)d_in[9];
    const float* bfc  = (const float*)d_in[10];

    char* ws = (char*)d_ws;
    uint32_t* xb  = (uint32_t*)(ws + XB_OFF);
    uint4*    h0b = (uint4*)(ws + H0_OFF);
    uint4*    h1b = (uint4*)(ws + H1_OFF);
    uint32_t* a0p = (uint32_t*)(ws + A0_OFF);
    uint32_t* a1p = (uint32_t*)(ws + A1_OFF);

    // Sentinel-fill both h histories (0xFF bytes -> every 8B word = SENT until
    // written; packed finite fp16 can never equal SENT). Adjacent: one memset.
    hipMemsetAsync(h0b, 0xFF, 2ULL * 33554432ULL, stream);

    hipLaunchKernelGGL(pack_x, dim3(TN * 16), dim3(256), 0, stream, x, xb);
    hipLaunchKernelGGL(pack_a, dim3(32 * 4 * 20), dim3(256), 0, stream, Wih0, Whh0, 128, 20, a0p);
    hipLaunchKernelGGL(pack_a, dim3(32 * 4 * 32), dim3(256), 0, stream, Wih1, Whh1, 512, 32, a1p);

    const uint4* xbc = (const uint4*)xb;
    const uint4* a0c = (const uint4*)a0p;
    const uint4* a1c = (const uint4*)a1p;
    void* args[] = { &xbc, &h0b, &h1b, &a0c, &a1c,
                     &bih0, &bhh0, &bih1, &bhh1 };
    hipLaunchCooperativeKernel((void*)lstm2, dim3(64), dim3(512), args, 0, stream);

    hipLaunchKernelGGL(fc_kernel, dim3(128), dim3(256), 0, stream,
                       (const uint16_t*)h1b, Wfc, bfc, (float*)d_out);
}